// Round 1
// baseline (16619.173 us; speedup 1.0000x reference)
//
#include <hip/hip_runtime.h>
#include <hip/hip_bf16.h>
#include <math.h>

typedef __attribute__((ext_vector_type(8))) short bf16x8;
typedef __attribute__((ext_vector_type(4))) float f32x4;

static __device__ inline short f2bf(float f) {
    unsigned u = __builtin_bit_cast(unsigned, f);
    u += 0x7fffu + ((u >> 16) & 1u);   // RNE
    return (short)(u >> 16);
}

// ---------------- init / conversion ----------------

__global__ void init_kernel(float* c_buf, float* sumexp) {
    int i = blockIdx.x * 256 + threadIdx.x;
    if (i < 64 * 512) c_buf[i] = 0.f;
    if (i < 127 * 64) sumexp[i] = 0.f;
}

// combined [2048][1024] bf16, rows reordered n' = h*4+g, cols = [Wih | Whh]
__global__ void conv_lstm_w(short* dst, const float* __restrict__ Wih,
                            const float* __restrict__ Whh) {
    int idx = blockIdx.x * 256 + threadIdx.x;      // < 2048*1024
    int np = idx >> 10, k = idx & 1023;
    int h = np >> 2, g = np & 3;
    int src = (g * 512 + h) * 512;
    float v = (k < 512) ? Wih[src + k] : Whh[src + k - 512];
    dst[idx] = f2bf(v);
}

__global__ void conv_plain(short* dst, const float* __restrict__ src, int n) {
    int idx = blockIdx.x * 256 + threadIdx.x;
    if (idx < n) dst[idx] = f2bf(src[idx]);
}

// ---------------- LSTM step (MFMA gates + fused pointwise) ----------------
// grid 32 blocks: block handles all 64 b, 16 h (64 reordered gate rows), K=1024.
__global__ __launch_bounds__(256) void lstm_kernel(
    const short* __restrict__ Wbf,      // [2048][1024] bf16 reordered
    const float* __restrict__ bih, const float* __restrict__ bhh,
    const int* __restrict__ words, int wstride,
    const float* __restrict__ embed,    // [V][512] f32
    const float* __restrict__ h_prev,   // [64][512] f32 or nullptr (zeros)
    float* __restrict__ c_buf,          // [64][512] in/out
    float* __restrict__ h_out)          // [64][512]
{
    __shared__ short xh[64 * 264];      // bf16 tile [64][256] pad 8
    __shared__ float gsm[64 * 65];
    __shared__ int words_sm[64];
    const int tid = threadIdx.x;
    if (tid < 64) words_sm[tid] = words[tid * wstride];

    const int lane = tid & 63, wave = tid >> 6;
    const int wm = wave >> 1, wn = wave & 1;
    const int l16 = lane & 15, lq = lane >> 4;
    const int n0 = blockIdx.x * 64;

    f32x4 acc[2][2] = {};

    for (int kt = 0; kt < 4; ++kt) {
        __syncthreads();  // protect prior tile reads (and words_sm at kt=0)
        // stage xh tile: k in [kt*256, kt*256+256)
        for (int i = 0; i < 16; ++i) {
            int e4 = i * 256 + tid;           // 4096 float4s
            int row = e4 >> 6, q = e4 & 63;
            int kloc = q * 4, k = kt * 256 + kloc;
            float4 v;
            if (k < 512) {
                v = *(const float4*)(embed + (long)words_sm[row] * 512 + k);
            } else if (h_prev) {
                v = *(const float4*)(h_prev + row * 512 + (k - 512));
            } else {
                v = make_float4(0.f, 0.f, 0.f, 0.f);
            }
            ushort4 s;
            s.x = (unsigned short)f2bf(v.x); s.y = (unsigned short)f2bf(v.y);
            s.z = (unsigned short)f2bf(v.z); s.w = (unsigned short)f2bf(v.w);
            *(ushort4*)&xh[row * 264 + kloc] = s;
        }
        __syncthreads();
        for (int ks = 0; ks < 8; ++ks) {
            int kg = kt * 256 + ks * 32;
            bf16x8 a[2], b[2];
            for (int mt = 0; mt < 2; ++mt)
                a[mt] = *(const bf16x8*)&xh[(wm * 32 + mt * 16 + l16) * 264 + ks * 32 + lq * 8];
            for (int nt = 0; nt < 2; ++nt)
                b[nt] = *(const bf16x8*)(Wbf + (long)(n0 + wn * 32 + nt * 16 + l16) * 1024 + kg + lq * 8);
            for (int mt = 0; mt < 2; ++mt)
                for (int nt = 0; nt < 2; ++nt)
                    acc[mt][nt] = __builtin_amdgcn_mfma_f32_16x16x32_bf16(a[mt], b[nt], acc[mt][nt], 0, 0, 0);
        }
    }
    __syncthreads();
    for (int mt = 0; mt < 2; ++mt)
        for (int nt = 0; nt < 2; ++nt)
            for (int r = 0; r < 4; ++r) {
                int m = wm * 32 + mt * 16 + lq * 4 + r;
                int n = wn * 32 + nt * 16 + l16;
                gsm[m * 65 + n] = acc[mt][nt][r];
            }
    __syncthreads();
    const int h0 = blockIdx.x * 16;
    for (int q = 0; q < 4; ++q) {
        int it = q * 256 + tid;
        int b = it & 63, hl = it >> 6;      // hl 0..15
        int hg = h0 + hl;
        float ig = gsm[b * 65 + hl * 4 + 0] + bih[hg]          + bhh[hg];
        float fg = gsm[b * 65 + hl * 4 + 1] + bih[512 + hg]    + bhh[512 + hg];
        float gg = gsm[b * 65 + hl * 4 + 2] + bih[1024 + hg]   + bhh[1024 + hg];
        float og = gsm[b * 65 + hl * 4 + 3] + bih[1536 + hg]   + bhh[1536 + hg];
        float si = 1.f / (1.f + __expf(-ig));
        float sf = 1.f / (1.f + __expf(-fg));
        float so = 1.f / (1.f + __expf(-og));
        float tg = tanhf(gg);
        float cold = c_buf[b * 512 + hg];
        float c2 = sf * cold + si * tg;
        float h2 = so * tanhf(c2);
        if (words_sm[b] == 0) {
            c2 = cold;
            h2 = h_prev ? h_prev[b * 512 + hg] : 0.f;
        }
        c_buf[b * 512 + hg] = c2;
        h_out[b * 512 + hg] = h2;
    }
}

// ---------------- attention: scores + softmax + ctx, writes cat=[ctx|h2] ----------------
__global__ __launch_bounds__(256) void attn_kernel(
    const float* __restrict__ h2,      // [64][512]
    const float* __restrict__ enc_hs,  // [128][64][512]
    const int* __restrict__ source,    // [64][128]
    float* __restrict__ cat)           // [64][1024]
{
    __shared__ float h2s[512];
    __shared__ float sc[128];
    const int b = blockIdx.x, tid = threadIdx.x;
    h2s[tid] = h2[b * 512 + tid];
    h2s[tid + 256] = h2[b * 512 + tid + 256];
    __syncthreads();
    const int wave = tid >> 6, lane = tid & 63;
    for (int i = 0; i < 32; ++i) {
        int t = wave * 32 + i;
        const float* p = enc_hs + t * 32768 + b * 512 + lane * 8;
        float4 u = *(const float4*)p;
        float4 w = *(const float4*)(p + 4);
        const float* hq = h2s + lane * 8;
        float v = u.x * hq[0] + u.y * hq[1] + u.z * hq[2] + u.w * hq[3]
                + w.x * hq[4] + w.y * hq[5] + w.z * hq[6] + w.w * hq[7];
        for (int off = 32; off; off >>= 1) v += __shfl_xor(v, off);
        if (lane == 0) sc[t] = (source[b * 128 + t] != 0) ? v : -1e30f;
    }
    __syncthreads();
    if (tid < 64) {
        float s0 = sc[tid], s1 = sc[tid + 64];
        float mx = fmaxf(s0, s1);
        for (int off = 32; off; off >>= 1) mx = fmaxf(mx, __shfl_xor(mx, off));
        float e0 = __expf(s0 - mx), e1 = __expf(s1 - mx);
        float sm = e0 + e1;
        for (int off = 32; off; off >>= 1) sm += __shfl_xor(sm, off);
        sc[tid] = e0 / sm;
        sc[tid + 64] = e1 / sm;
    }
    __syncthreads();
    float a0 = 0.f, a1 = 0.f;
    #pragma unroll 4
    for (int t = 0; t < 128; ++t) {
        float w = sc[t];
        a0 += w * enc_hs[t * 32768 + b * 512 + tid];
        a1 += w * enc_hs[t * 32768 + b * 512 + 256 + tid];
    }
    cat[b * 1024 + tid] = a0;
    cat[b * 1024 + 256 + tid] = a1;
    cat[b * 1024 + 512 + tid] = h2s[tid];
    cat[b * 1024 + 768 + tid] = h2s[tid + 256];
}

// ---------------- ha = tanh(cat @ attn_W^T + b) -> bf16 ----------------
__global__ __launch_bounds__(256) void ha_kernel(
    const float* __restrict__ cat,   // [64][1024]
    const short* __restrict__ Wa,    // [512][1024] bf16
    const float* __restrict__ ab,    // [512]
    short* __restrict__ ha)          // [64][512] bf16
{
    __shared__ short xh[64 * 264];
    const int tid = threadIdx.x, lane = tid & 63, wave = tid >> 6;
    const int wm = wave >> 1, wn = wave & 1, l16 = lane & 15, lq = lane >> 4;
    const int n0 = blockIdx.x * 64;
    f32x4 acc[2][2] = {};
    for (int kt = 0; kt < 4; ++kt) {
        __syncthreads();
        for (int i = 0; i < 16; ++i) {
            int e4 = i * 256 + tid;
            int row = e4 >> 6, q = e4 & 63;
            int kloc = q * 4, k = kt * 256 + kloc;
            float4 v = *(const float4*)(cat + row * 1024 + k);
            ushort4 s;
            s.x = (unsigned short)f2bf(v.x); s.y = (unsigned short)f2bf(v.y);
            s.z = (unsigned short)f2bf(v.z); s.w = (unsigned short)f2bf(v.w);
            *(ushort4*)&xh[row * 264 + kloc] = s;
        }
        __syncthreads();
        for (int ks = 0; ks < 8; ++ks) {
            bf16x8 a[2], b[2];
            for (int mt = 0; mt < 2; ++mt)
                a[mt] = *(const bf16x8*)&xh[(wm * 32 + mt * 16 + l16) * 264 + ks * 32 + lq * 8];
            for (int nt = 0; nt < 2; ++nt)
                b[nt] = *(const bf16x8*)(Wa + (long)(n0 + wn * 32 + nt * 16 + l16) * 1024 + kt * 256 + ks * 32 + lq * 8);
            for (int mt = 0; mt < 2; ++mt)
                for (int nt = 0; nt < 2; ++nt)
                    acc[mt][nt] = __builtin_amdgcn_mfma_f32_16x16x32_bf16(a[mt], b[nt], acc[mt][nt], 0, 0, 0);
        }
    }
    for (int mt = 0; mt < 2; ++mt)
        for (int nt = 0; nt < 2; ++nt)
            for (int r = 0; r < 4; ++r) {
                int m = wm * 32 + mt * 16 + lq * 4 + r;
                int n = n0 + wn * 32 + nt * 16 + l16;
                ha[m * 512 + n] = f2bf(tanhf(acc[mt][nt][r] + ab[n]));
            }
}

// ---------------- vocab projection + streaming sumexp / target-logit ----------------
// grid 125 blocks x 256n each; K=512; no LDS staging (A,B from L2).
__global__ __launch_bounds__(256) void logits_kernel(
    const short* __restrict__ ha,    // [64][512] bf16
    const short* __restrict__ Wo,    // [32000][512] bf16
    const float* __restrict__ ob,    // [32000]
    const int* __restrict__ target,  // [64][128]
    int t,
    float* __restrict__ sumexp,      // [127][64]
    float* __restrict__ logit_t)     // [127][64]
{
    __shared__ float se[64];
    const int tid = threadIdx.x, lane = tid & 63, wave = tid >> 6;
    const int wm = wave >> 1, wn = wave & 1;
    const int l16 = lane & 15, lq = lane >> 4;
    const int n0 = blockIdx.x * 256;
    f32x4 acc[2][8] = {};
    for (int ks = 0; ks < 16; ++ks) {
        bf16x8 a[2];
        for (int mt = 0; mt < 2; ++mt)
            a[mt] = *(const bf16x8*)(ha + (wm * 32 + mt * 16 + l16) * 512 + ks * 32 + lq * 8);
        for (int nt = 0; nt < 8; ++nt) {
            int v = n0 + wn * 128 + nt * 16 + l16;
            bf16x8 bb = *(const bf16x8*)(Wo + (long)v * 512 + ks * 32 + lq * 8);
            for (int mt = 0; mt < 2; ++mt)
                acc[mt][nt] = __builtin_amdgcn_mfma_f32_16x16x32_bf16(a[mt], bb, acc[mt][nt], 0, 0, 0);
        }
    }
    if (tid < 64) se[tid] = 0.f;
    __syncthreads();
    for (int mt = 0; mt < 2; ++mt) {
        for (int r = 0; r < 4; ++r) {
            int b = wm * 32 + mt * 16 + lq * 4 + r;
            int tw = target[b * 128 + t + 1];
            float partial = 0.f;
            for (int nt = 0; nt < 8; ++nt) {
                int n = n0 + wn * 128 + nt * 16 + l16;
                float val = acc[mt][nt][r] + ob[n];
                partial += __expf(val);
                if (n == tw) logit_t[t * 64 + b] = val;
            }
            for (int m = 1; m < 16; m <<= 1) partial += __shfl_xor(partial, m);
            if (l16 == 0) atomicAdd(&se[b], partial);
        }
    }
    __syncthreads();
    if (tid < 64) atomicAdd(&sumexp[t * 64 + tid], se[tid]);
}

// ---------------- final loss ----------------
__global__ void loss_kernel(const float* __restrict__ sumexp,
                            const float* __restrict__ logit_t,
                            const int* __restrict__ target,
                            float* __restrict__ out)
{
    __shared__ float red[128];
    const int tid = threadIdx.x;
    float local = 0.f;
    if (tid < 127) {
        float s = 0.f; int cnt = 0;
        for (int b = 0; b < 64; ++b) {
            int w = target[b * 128 + tid + 1];
            if (w != 0) {
                s += logf(sumexp[tid * 64 + b]) - logit_t[tid * 64 + b];
                cnt++;
            }
        }
        int c = cnt > 1 ? cnt : 1;
        local = s / (float)c;
    }
    red[tid] = local;
    __syncthreads();
    if (tid == 0) {
        float tot = 0.f;
        for (int i = 0; i < 127; ++i) tot += red[i];
        out[0] = tot;
    }
}

// ---------------- host launcher ----------------
extern "C" void kernel_launch(void* const* d_in, const int* in_sizes, int n_in,
                              void* d_out, int out_size, void* d_ws, size_t ws_size,
                              hipStream_t stream)
{
    (void)in_sizes; (void)n_in; (void)out_size; (void)ws_size;
    const int*   source = (const int*)  d_in[0];
    const int*   target = (const int*)  d_in[1];
    const float* embS   = (const float*)d_in[2];
    const float* embT   = (const float*)d_in[3];
    const float* eWih   = (const float*)d_in[4];
    const float* eWhh   = (const float*)d_in[5];
    const float* ebih   = (const float*)d_in[6];
    const float* ebhh   = (const float*)d_in[7];
    const float* dWih   = (const float*)d_in[8];
    const float* dWhh   = (const float*)d_in[9];
    const float* dbih   = (const float*)d_in[10];
    const float* dbhh   = (const float*)d_in[11];
    const float* attnW  = (const float*)d_in[12];
    const float* attnb  = (const float*)d_in[13];
    const float* outW   = (const float*)d_in[14];
    const float* outb   = (const float*)d_in[15];
    float* out = (float*)d_out;
    char* ws = (char*)d_ws;

    float* enc_hs = (float*)(ws);                      // [128][64][512] 16 MB
    float* c_buf  = (float*)(ws + 16777216);           // [64][512]
    float* dec_h0 = (float*)(ws + 16908288);
    float* dec_h1 = (float*)(ws + 17039360);
    float* cat    = (float*)(ws + 17170432);           // [64][1024]
    float* sumexp = (float*)(ws + 17432576);           // [127][64]
    float* logitt = (float*)(ws + 17465088);           // [127][64]
    short* ha_bf  = (short*)(ws + 17497600);           // [64][512] bf16
    short* Wenc   = (short*)(ws + 17563136);           // [2048][1024] bf16
    short* Wdec   = (short*)(ws + 21757440);
    short* Wattn  = (short*)(ws + 25951744);           // [512][1024] bf16
    short* Wout   = (short*)(ws + 27000320);           // [32000][512] bf16

    init_kernel<<<128, 256, 0, stream>>>(c_buf, sumexp);
    conv_lstm_w<<<8192, 256, 0, stream>>>(Wenc, eWih, eWhh);
    conv_lstm_w<<<8192, 256, 0, stream>>>(Wdec, dWih, dWhh);
    conv_plain<<<2048, 256, 0, stream>>>(Wattn, attnW, 512 * 1024);
    conv_plain<<<64000, 256, 0, stream>>>(Wout, outW, 32000 * 512);

    for (int t = 0; t < 128; ++t) {
        lstm_kernel<<<32, 256, 0, stream>>>(
            Wenc, ebih, ebhh, source + t, 128, embS,
            t ? enc_hs + (long)(t - 1) * 32768 : nullptr,
            c_buf, enc_hs + (long)t * 32768);
    }
    for (int t = 0; t < 127; ++t) {
        const float* hp = t ? (((t - 1) & 1) ? dec_h1 : dec_h0)
                            : enc_hs + (long)127 * 32768;
        float* ho = (t & 1) ? dec_h1 : dec_h0;
        lstm_kernel<<<32, 256, 0, stream>>>(
            Wdec, dbih, dbhh, target + t, 128, embT, hp, c_buf, ho);
        attn_kernel<<<64, 256, 0, stream>>>(ho, enc_hs, source, cat);
        ha_kernel<<<8, 256, 0, stream>>>(cat, Wattn, attnb, ha_bf);
        logits_kernel<<<125, 256, 0, stream>>>(ha_bf, Wout, outb, target, t, sumexp, logitt);
    }
    loss_kernel<<<1, 128, 0, stream>>>(sumexp, logitt, target, out);
}